// Round 10
// baseline (111.761 us; speedup 1.0000x reference)
//
#include <hip/hip_runtime.h>

#define BB 16
#define PP 131072
#define GG 64
#define THRESH 0.35f
#define RMAX 0.086f          // max prior half-extent 0.085 + slop margin
#define NCH 32               // match/loss chunks per image
#define CPR 4096             // priors per match/loss chunk
#define NCT 16               // tail chunks per image
#define CPT 8192             // priors per tail chunk

// ---------------- workspace layout (bytes) ----------------
// No host-side zeroing anywhere: partials are unconditional stores; sync
// state (cidx/negs/arr/done) is zeroed by k_loss, visible at kernel boundary.
#define OFF_BESTP   0          // u64[BB][NCH][64]  262144
#define OFF_H1TOT   262144     // u32[BB][4096]     262144  (zeroed by k_match)
#define OFF_NPOSP   524288     // i32[BB][NCH]      2048
#define OFF_PCP     526336     // f32[BB][NCH]      2048
#define OFF_LOCP    528384     // f32[BB][NCH]      2048
#define OFF_CIDX    530432     // u32[BB]           64
#define OFF_NEGS    530496     // f32[BB]           64
#define OFF_ARR     530560     // u32[BB]           64
#define OFF_DONE    530624     // u32               64
#define OFF_RESN    530688     // i32[BB]
#define OFF_RESK    530752     // i32[BB]
#define OFF_RESC    530816     // f32[BB]
#define OFF_RESL    530880     // f32[BB]
#define OFF_PU8     530944     // u8[BB*PP]   2097152
#define OFF_KEYS    2628096    // u32[BB*PP]  8388608
#define OFF_CAND    11016704   // u32[BB*PP]  8388608   (total ~19.4 MB)

// ---------------- kernel 1: raster mask + match ----------------
// grid (NCH, BB) x 1024; 4 priors/thread strided by 1024; 2 blocks/CU.
__global__ __launch_bounds__(1024, 8) void k_match(
    const float* __restrict__ priorbox, const float* __restrict__ targets,
    unsigned long long* __restrict__ bestp, unsigned char* __restrict__ pu8,
    unsigned* __restrict__ h1tot)
{
    __shared__ unsigned msk[8192];                      // u64 mask per cell, interleaved
    __shared__ float4 gxy[GG];
    __shared__ unsigned long long sbest[GG];
    const int b = blockIdx.y, chunk = blockIdx.x, tid = threadIdx.x;

    if (tid < 128) h1tot[b * 4096 + chunk * 128 + tid] = 0u;   // 32 chunks x 128 = 4096
    for (int i = tid; i < 8192; i += 1024) msk[i] = 0u;
    if (tid < GG) {
        const float* t = targets + (size_t)(b * GG + tid) * 5;
        gxy[tid] = make_float4(t[1], t[0], t[3], t[2]); // gts = t[[1,0,3,2]]
        sbest[tid] = 0ull;
    }
    __syncthreads();

    {   // rasterize expanded gt boxes into the 64x64 cell bitmask
        const int g = tid & 63, strip = tid >> 6;
        float4 a = gxy[g];
        int cx0 = max(0, (int)((a.x - RMAX) * 64.f));
        int cx1 = min(63, (int)ceilf((a.z + RMAX) * 64.f) - 1);
        int cy0 = max(0, (int)((a.y - RMAX) * 64.f));
        int cy1 = min(63, (int)ceilf((a.w + RMAX) * 64.f) - 1);
        unsigned bit = 1u << (g & 31);
        const int word = (g >> 5);
        for (int cy = cy0 + strip; cy <= cy1; cy += 16)
            for (int cx = cx0; cx <= cx1; cx++)
                atomicOr(&msk[2 * (cy * 64 + cx) + word], bit);
    }
    __syncthreads();

#pragma unroll
    for (int j = 0; j < 4; j++) {
        const int p = chunk * CPR + j * 1024 + tid;
        float4 pr = *reinterpret_cast<const float4*>(priorbox + (size_t)p * 4);
        float hx = 0.5f * pr.z, hy = 0.5f * pr.w;
        float px1 = pr.x - hx, py1 = pr.y - hy;
        float px2 = pr.x + hx, py2 = pr.y + hy;
        float par = (px2 - px1) * (py2 - py1);
        int cx = min(63, max(0, (int)(pr.x * 64.f)));
        int cy = min(63, max(0, (int)(pr.y * 64.f)));
        uint2 mm = *reinterpret_cast<uint2*>(&msk[2 * (cy * 64 + cx)]);
        unsigned long long m = ((unsigned long long)mm.y << 32) | mm.x;
        const unsigned long long notp = (unsigned long long)(~(unsigned)p);
        float bv = -1.f; int bg = 0;
        while (m) {
            // two set bits per iteration: two independent LDS reads in flight
            const int g0 = __ffsll(m) - 1; m &= m - 1;
            const bool has1 = (m != 0ull);
            const int g1 = has1 ? (__ffsll(m) - 1) : g0;
            if (has1) m &= m - 1;
            float4 a0 = gxy[g0];
            float4 a1 = gxy[g1];
            float w0 = fmaxf(fminf(a0.z, px2) - fmaxf(a0.x, px1), 0.f);
            float h0 = fmaxf(fminf(a0.w, py2) - fmaxf(a0.y, py1), 0.f);
            float w1 = fmaxf(fminf(a1.z, px2) - fmaxf(a1.x, px1), 0.f);
            float h1 = fmaxf(fminf(a1.w, py2) - fmaxf(a1.y, py1), 0.f);
            float ar0 = (a0.z - a0.x) * (a0.w - a0.y);
            float ar1 = (a1.z - a1.x) * (a1.w - a1.y);
            float i0 = w0 * h0, i1 = w1 * h1;
            float v0 = i0 * __builtin_amdgcn_rcpf(ar0 + par - i0);
            float v1 = i1 * __builtin_amdgcn_rcpf(ar1 + par - i1);
            if (v0 > bv) { bv = v0; bg = g0; }          // ascending g: first-max kept
            if (has1 && v1 > bv) { bv = v1; bg = g1; }
            if (v0 > 0.f)
                atomicMax(&sbest[g0],
                          (((unsigned long long)__float_as_uint(v0)) << 32) | notp);
            if (has1 && v1 > 0.f)
                atomicMax(&sbest[g1],
                          (((unsigned long long)__float_as_uint(v1)) << 32) | notp);
        }
        pu8[(size_t)b * PP + p] = (unsigned char)(bg | ((bv >= THRESH) ? 0x80 : 0));
    }

    __syncthreads();
    if (tid < GG) bestp[(b * NCH + chunk) * GG + tid] = sbest[tid];   // plain store
}

// ---------------- kernel 2: reduce bestp + loss + keys + global hist ----------------
// grid (NCH, BB) x 1024; 4 priors/thread strided by 1024.
__global__ __launch_bounds__(1024, 8) void k_loss(
    const float* __restrict__ loc_preds, const float* __restrict__ cls_preds,
    const float* __restrict__ priorbox, const float* __restrict__ targets,
    const unsigned long long* __restrict__ bestp, const unsigned char* __restrict__ pu8,
    unsigned* __restrict__ keys, unsigned* __restrict__ h1tot,
    int* __restrict__ nposp, float* __restrict__ pcp, float* __restrict__ locp,
    unsigned* __restrict__ cidx, float* __restrict__ negs,
    unsigned* __restrict__ arr, unsigned* __restrict__ done)
{
    __shared__ unsigned long long tmp64[2048];
    __shared__ unsigned hcnt[4096];
    __shared__ float4 gxy[GG];
    __shared__ float glab[GG];
    __shared__ unsigned blist[GG];
    __shared__ int nb;
    __shared__ float sred[32];
    __shared__ int sredi[16];
    const int b = blockIdx.y, chunk = blockIdx.x, tid = threadIdx.x;
    const int lane = tid & 63, wid = tid >> 6;

    if (tid == 0 && chunk == 0) {                      // zero sync state for k_tail
        cidx[b] = 0u; negs[b] = 0.f; arr[b] = 0u;
        if (b == 0) *done = 0u;
    }

    tmp64[tid]        = bestp[(b * NCH + (tid >> 6)) * GG + (tid & 63)];
    tmp64[tid + 1024] = bestp[(b * NCH + 16 + (tid >> 6)) * GG + (tid & 63)];
    for (int i = tid; i < 4096; i += 1024) hcnt[i] = 0u;
    if (tid < GG) {
        const float* t = targets + (size_t)(b * GG + tid) * 5;
        gxy[tid] = make_float4(t[1], t[0], t[3], t[2]);
        glab[tid] = t[4];
    }
    __syncthreads();
    for (int s = 16; s > 0; s >>= 1) {                 // reduce chunk dim 32 -> 1
        if (tid < s * 64) {
            const int c = tid >> 6, g = tid & 63;
            unsigned long long a = tmp64[c * 64 + g], d = tmp64[(c + s) * 64 + g];
            tmp64[c * 64 + g] = d > a ? d : a;
        }
        __syncthreads();
    }
    if (tid == 0) {
        int n = 0;
        for (int g = 0; g < GG; g++) {                 // ascending g: later-g wins
            unsigned long long m = tmp64[g];
            if (m) {
                unsigned p = ~((unsigned)(m & 0xFFFFFFFFull));
                if ((int)(p >> 12) == chunk)
                    blist[n++] = (((p & (CPR - 1)) << 6) | (unsigned)g);
            }
        }
        nb = n;
    }
    __syncthreads();

    const int nbl = nb;
    float locpart = 0.f, clspart = 0.f; int cnt = 0;
#pragma unroll
    for (int j = 0; j < 4; j++) {
        const int plocal = j * 1024 + tid;
        const size_t ip = (size_t)b * PP + chunk * CPR + plocal;
        const unsigned m8 = pu8[ip];
        int g = m8 & 63;
        bool pos = (m8 >> 7) != 0;
        for (int i = 0; i < nbl; i++) {
            unsigned e = blist[i];
            if ((int)(e >> 6) == plocal) { pos = true; g = (int)(e & 63u); }
        }
        const float2 cl = *reinterpret_cast<const float2*>(cls_preds + ip * 2);
        const float mx = fmaxf(cl.x, cl.y);
        const float lse = mx + log1pf(expf(fminf(cl.x, cl.y) - mx));
        unsigned key = 0u;
        if (pos && glab[g] > 0.f) {
            float gathered = (((int)glab[g]) == 0) ? cl.x : cl.y;
            clspart += lse - gathered;
            cnt++;
            const int p = chunk * CPR + plocal;
            float4 pr = *reinterpret_cast<const float4*>(priorbox + (size_t)p * 4);
            float4 gt = gxy[g];
            float gcx = ((gt.x + gt.z) * 0.5f - pr.x) / (0.1f * pr.z);
            float gcy = ((gt.y + gt.w) * 0.5f - pr.y) / (0.1f * pr.w);
            float gw = logf((gt.z - gt.x) / pr.z) / 0.2f;
            float gh = logf((gt.w - gt.y) / pr.w) / 0.2f;
            float4 lp = *reinterpret_cast<const float4*>(loc_preds + ip * 4);
            float d0 = lp.x - gcx, d1 = lp.y - gcy, d2 = lp.z - gw, d3 = lp.w - gh;
            float a0 = fabsf(d0), a1 = fabsf(d1), a2 = fabsf(d2), a3 = fabsf(d3);
            locpart += ((a0 < 1.f) ? 0.5f * d0 * d0 : a0 - 0.5f)
                     + ((a1 < 1.f) ? 0.5f * d1 * d1 : a1 - 0.5f)
                     + ((a2 < 1.f) ? 0.5f * d2 * d2 : a2 - 0.5f)
                     + ((a3 < 1.f) ? 0.5f * d3 * d3 : a3 - 0.5f);
        } else {
            float lc = lse - cl.x;                     // > 0 strictly for negs
            key = __float_as_uint(lc);
            atomicAdd(&hcnt[key >> 20], 1u);           // counts only (sums via k_tail regs)
        }
        keys[ip] = key;
    }

    for (int o = 32; o; o >>= 1) {
        locpart += __shfl_xor(locpart, o);
        clspart += __shfl_xor(clspart, o);
        cnt     += __shfl_xor(cnt, o);
    }
    if (lane == 0) { sred[wid] = locpart; sred[16 + wid] = clspart; sredi[wid] = cnt; }
    __syncthreads();
    if (tid == 0) {
        float l = 0.f, c = 0.f; int n = 0;
        for (int i = 0; i < 16; i++) { l += sred[i]; c += sred[16 + i]; n += sredi[i]; }
        nposp[b * NCH + chunk] = n;                    // unconditional: no init needed
        pcp[b * NCH + chunk] = c;
        locp[b * NCH + chunk] = l;
    }
    __syncthreads();
    for (int i = tid; i < 4096; i += 1024) {           // ~400 nonzero bins/block
        unsigned cc = hcnt[i];
        if (cc) atomicAdd(&h1tot[b * 4096 + i], cc);
    }
}

// ---------------- parallel descending k-th finder (1024-thread block) ----------------
template <int NBINS>
__device__ void find_kth_par(const unsigned* __restrict__ h, int k, int* sel, int* krem)
{
    constexpr int PER = NBINS / 1024;
    __shared__ unsigned wsum_[16];
    __shared__ int res_[2];
    const int tid = threadIdx.x, lane = tid & 63, wid = tid >> 6;
    __syncthreads();
    unsigned own[PER];
    unsigned s = 0;
#pragma unroll
    for (int i = 0; i < PER; i++) { own[i] = h[NBINS - 1 - (tid * PER + i)]; s += own[i]; }
    unsigned incl = s;
    for (int d = 1; d < 64; d <<= 1) {
        unsigned t = __shfl_up(incl, d);
        if (lane >= d) incl += t;
    }
    if (lane == 63) wsum_[wid] = incl;
    if (tid == 0) { res_[0] = -1; res_[1] = 0; }
    __syncthreads();
    unsigned woff = 0;
    for (int w = 0; w < 16; w++) woff += (w < wid) ? wsum_[w] : 0u;
    const unsigned texcl = woff + incl - s;
    if (k > 0 && texcl < (unsigned)k && texcl + s >= (unsigned)k) {
        unsigned run = texcl;
#pragma unroll
        for (int i = 0; i < PER; i++) {
            run += own[i];
            if (run >= (unsigned)k) {
                res_[0] = NBINS - 1 - (tid * PER + i);
                res_[1] = k - (int)(run - own[i]);
                break;
            }
        }
    }
    __syncthreads();
    *sel = res_[0]; *krem = res_[1];
}

__device__ float block_sum_f(float v)
{
    __shared__ float rs[16];
    const int tid = threadIdx.x;
    __syncthreads();
    for (int o = 32; o; o >>= 1) v += __shfl_xor(v, o);
    if ((tid & 63) == 0) rs[tid >> 6] = v;
    __syncthreads();
    float s = 0.f;
    for (int i = 0; i < 16; i++) s += rs[i];
    return s;
}

// ---------------- kernel 3: compact + negsum; last block/image does select+final ----
// grid (NCT, BB) x 1024, 8 keys/thread.
__global__ __launch_bounds__(1024) void k_tail(
    const unsigned* __restrict__ keys, const unsigned* __restrict__ h1tot,
    const int* __restrict__ nposp, const float* __restrict__ pcp,
    const float* __restrict__ locp, unsigned* __restrict__ cand,
    unsigned* __restrict__ cidx, float* __restrict__ negs,
    unsigned* __restrict__ arr, unsigned* __restrict__ done,
    int* __restrict__ resn, int* __restrict__ resk,
    float* __restrict__ resc, float* __restrict__ resl, float* __restrict__ out)
{
    __shared__ unsigned wcnt[16], wbase[16];
    __shared__ unsigned bbase;
    __shared__ int snp, lastflag;
    __shared__ unsigned ch[1024];
    __shared__ float cs[1024];
    const int b = blockIdx.y, chunk = blockIdx.x, tid = threadIdx.x;
    const int lane = tid & 63, wid = tid >> 6;

    if (tid == 0) {
        int np = 0;
        for (int c = 0; c < NCH; c++) np += nposp[b * NCH + c];
        snp = np;
    }
    unsigned kv[8];
#pragma unroll
    for (int j = 0; j < 8; j++)
        kv[j] = keys[(size_t)b * PP + chunk * CPT + j * 1024 + tid];
    __syncthreads();
    const int np = snp;
    const int k = min(3 * np, PP - 1);
    int sel1, kk1;
    find_kth_par<4096>(h1tot + b * 4096, k, &sel1, &kk1);
    const unsigned s1 = (unsigned)sel1;                // -1 matches nothing

    // negsum over buckets strictly above sel1, straight from registers
    float nv = 0.f;
    if (sel1 >= 0) {
#pragma unroll
        for (int j = 0; j < 8; j++)
            if ((kv[j] >> 20) > s1) nv += __uint_as_float(kv[j]);
    }
    float nsum = block_sum_f(nv);
    if (tid == 0 && nsum != 0.f) atomicAdd(&negs[b], nsum);   // 16 adds/address

    // compact bucket-sel1 keys: 1 returning atomic per block
    unsigned long long mv[8];
    unsigned wn = 0;
#pragma unroll
    for (int j = 0; j < 8; j++) {
        mv[j] = __ballot((kv[j] >> 20) == s1);
        wn += (unsigned)__popcll(mv[j]);
    }
    if (lane == 0) wcnt[wid] = wn;
    __syncthreads();
    if (tid == 0) {
        unsigned run = 0;
        for (int w = 0; w < 16; w++) { wbase[w] = run; run += wcnt[w]; }
        bbase = run ? atomicAdd(&cidx[b], run) : 0u;
    }
    __syncthreads();
    {
        unsigned run = bbase + wbase[wid];
        const unsigned long long lanemask = (1ull << lane) - 1ull;
#pragma unroll
        for (int j = 0; j < 8; j++) {
            if ((kv[j] >> 20) == s1)
                cand[(size_t)b * PP + run + (unsigned)__popcll(mv[j] & lanemask)] = kv[j];
            run += (unsigned)__popcll(mv[j]);
        }
    }

    // arrival: the 16th block of this image runs the select phase
    __syncthreads();
    if (tid == 0) {
        __threadfence();                               // release cand/negs writes
        unsigned old = atomicAdd(&arr[b], 1u);
        lastflag = (old == NCT - 1) ? 1 : 0;
    }
    __syncthreads();
    if (!lastflag) return;
    __threadfence();                                   // acquire other blocks' writes

    const unsigned ncand = cidx[b];
    ch[tid] = 0u; cs[tid] = 0.f;
    __syncthreads();
    for (unsigned i = tid; i < ncand; i += 1024) {
        unsigned v = cand[(size_t)b * PP + i];
        unsigned bin = (v >> 10) & 1023u;
        atomicAdd(&ch[bin], 1u);
        atomicAdd(&cs[bin], __uint_as_float(v));
    }
    __syncthreads();
    int sel2, kk2;
    find_kth_par<1024>(ch, (sel1 < 0) ? 0 : kk1, &sel2, &kk2);
    float sumhi2 = block_sum_f((sel2 >= 0 && tid > sel2) ? cs[tid] : 0.f);

    __syncthreads();
    ch[tid] = 0u; cs[tid] = 0.f;
    __syncthreads();
    if (sel2 >= 0) {
        for (unsigned i = tid; i < ncand; i += 1024) {
            unsigned v = cand[(size_t)b * PP + i];
            if (((v >> 10) & 1023u) == (unsigned)sel2) {
                atomicAdd(&ch[v & 1023u], 1u);
                atomicAdd(&cs[v & 1023u], __uint_as_float(v));
            }
        }
    }
    __syncthreads();
    int sel3, needeq;
    find_kth_par<1024>(ch, (sel2 < 0) ? 0 : kk2, &sel3, &needeq);
    float sumhi3 = block_sum_f((sel3 >= 0 && tid > sel3) ? cs[tid] : 0.f);

    if (tid == 0) {
        float pcsum = 0.f, locsum = 0.f;
        for (int c = 0; c < NCH; c++) {
            pcsum += pcp[b * NCH + c];
            locsum += locp[b * NCH + c];
        }
        float add = 0.f;
        if (sel3 >= 0 && needeq > 0) {
            unsigned Kstar = ((unsigned)sel1 << 20) | ((unsigned)sel2 << 10) | (unsigned)sel3;
            add = needeq * __uint_as_float(Kstar);
        }
        resn[b] = np;
        resk[b] = k;
        resc[b] = pcsum + negs[b] + sumhi2 + sumhi3 + add;
        resl[b] = locsum;
        __threadfence();
        unsigned old = atomicAdd(done, 1u);
        lastflag = (old == BB - 1) ? 1 : 0;
    }
    __syncthreads();
    if (!lastflag || tid != 0) return;

    __threadfence();
    volatile int* vrn = (volatile int*)resn;
    volatile int* vrk = (volatile int*)resk;
    volatile float* vrc = (volatile float*)resc;
    volatile float* vrl = (volatile float*)resl;
    int npt = 0; long long maskc = 0; float clsnum = 0.f, locnum = 0.f;
    for (int b2 = 0; b2 < BB; b2++) {
        npt += vrn[b2];
        maskc += (long long)vrn[b2] + vrk[b2];
        clsnum += vrc[b2];
        locnum += vrl[b2];
    }
    float denom_loc = (float)((4 * npt > 1) ? 4 * npt : 1);
    float denom_cls = (float)((maskc > 1) ? maskc : 1);
    float loss_loc = locnum / denom_loc;
    float loss_cls = clsnum / denom_cls;
    out[0] = (loss_cls + loss_loc) / (float)npt;
    out[1] = loss_loc;
    out[2] = loss_cls;
}

extern "C" void kernel_launch(void* const* d_in, const int* in_sizes, int n_in,
                              void* d_out, int out_size, void* d_ws, size_t ws_size,
                              hipStream_t stream)
{
    const float* loc_preds = (const float*)d_in[0];
    const float* cls_preds = (const float*)d_in[1];
    const float* priorbox  = (const float*)d_in[2];
    const float* targets   = (const float*)d_in[3];
    float* out = (float*)d_out;

    char* ws = (char*)d_ws;
    unsigned long long* bestp = (unsigned long long*)(ws + OFF_BESTP);
    unsigned* h1tot = (unsigned*)(ws + OFF_H1TOT);
    int*      nposp = (int*)(ws + OFF_NPOSP);
    float*    pcp   = (float*)(ws + OFF_PCP);
    float*    locp  = (float*)(ws + OFF_LOCP);
    unsigned* cidx  = (unsigned*)(ws + OFF_CIDX);
    float*    negs  = (float*)(ws + OFF_NEGS);
    unsigned* arr   = (unsigned*)(ws + OFF_ARR);
    unsigned* done  = (unsigned*)(ws + OFF_DONE);
    int*      resn  = (int*)(ws + OFF_RESN);
    int*      resk  = (int*)(ws + OFF_RESK);
    float*    resc  = (float*)(ws + OFF_RESC);
    float*    resl  = (float*)(ws + OFF_RESL);
    unsigned char* pu8 = (unsigned char*)(ws + OFF_PU8);
    unsigned* keys  = (unsigned*)(ws + OFF_KEYS);
    unsigned* cand  = (unsigned*)(ws + OFF_CAND);

    k_match<<<dim3(NCH, BB), 1024, 0, stream>>>(priorbox, targets, bestp, pu8, h1tot);
    k_loss<<<dim3(NCH, BB), 1024, 0, stream>>>(loc_preds, cls_preds, priorbox, targets,
                                               bestp, pu8, keys, h1tot,
                                               nposp, pcp, locp, cidx, negs, arr, done);
    k_tail<<<dim3(NCT, BB), 1024, 0, stream>>>(keys, h1tot, nposp, pcp, locp, cand,
                                               cidx, negs, arr, done,
                                               resn, resk, resc, resl, out);
}

// Round 11
// 96.742 us; speedup vs baseline: 1.1553x; 1.1553x over previous
//
#include <hip/hip_runtime.h>

#define BB 16
#define PP 131072
#define GG 64
#define THRESH 0.35f
#define RMAX 0.086f          // max prior half-extent 0.085 + slop margin
#define NCH 32               // match/loss chunks per image
#define CPR 4096             // priors per match/loss chunk
#define NCT 16               // tail chunks per image
#define CPT 8192             // priors per tail chunk

// ---------------- workspace layout (bytes) ----------------
// No host-side zeroing anywhere: partials are unconditional stores; sync
// state (cidx/negs/arr/done) is zeroed by k_loss, visible at kernel boundary.
#define OFF_BESTP   0          // u64[BB][NCH][64]  262144
#define OFF_H1TOT   262144     // u32[BB][4096]     262144  (zeroed by k_match)
#define OFF_NPOSP   524288     // i32[BB][NCH]      2048
#define OFF_PCP     526336     // f32[BB][NCH]      2048
#define OFF_LOCP    528384     // f32[BB][NCH]      2048
#define OFF_CIDX    530432     // u32[BB]           64
#define OFF_NEGS    530496     // f32[BB]           64
#define OFF_ARR     530560     // u32[BB]           64
#define OFF_DONE    530624     // u32               64
#define OFF_RESN    530688     // i32[BB]
#define OFF_RESK    530752     // i32[BB]
#define OFF_RESC    530816     // f32[BB]
#define OFF_RESL    530880     // f32[BB]
#define OFF_PU8     530944     // u8[BB*PP]   2097152
#define OFF_KEYS    2628096    // u32[BB*PP]  8388608
#define OFF_CAND    11016704   // u32[BB*PP]  8388608   (total ~19.4 MB)

// ---------------- kernel 1: raster mask + match ----------------
// grid (NCH, BB) x 1024; 4 priors/thread strided by 1024; 2 blocks/CU.
__global__ __launch_bounds__(1024, 8) void k_match(
    const float* __restrict__ priorbox, const float* __restrict__ targets,
    unsigned long long* __restrict__ bestp, unsigned char* __restrict__ pu8,
    unsigned* __restrict__ h1tot)
{
    __shared__ unsigned msk[8192];                      // u64 mask per cell, interleaved
    __shared__ float4 gxy[GG];
    __shared__ unsigned long long sbest[GG];
    const int b = blockIdx.y, chunk = blockIdx.x, tid = threadIdx.x;

    if (tid < 128) h1tot[b * 4096 + chunk * 128 + tid] = 0u;   // 32 chunks x 128 = 4096
    for (int i = tid; i < 8192; i += 1024) msk[i] = 0u;
    if (tid < GG) {
        const float* t = targets + (size_t)(b * GG + tid) * 5;
        gxy[tid] = make_float4(t[1], t[0], t[3], t[2]); // gts = t[[1,0,3,2]]
        sbest[tid] = 0ull;
    }
    __syncthreads();

    {   // rasterize expanded gt boxes into the 64x64 cell bitmask
        const int g = tid & 63, strip = tid >> 6;
        float4 a = gxy[g];
        int cx0 = max(0, (int)((a.x - RMAX) * 64.f));
        int cx1 = min(63, (int)ceilf((a.z + RMAX) * 64.f) - 1);
        int cy0 = max(0, (int)((a.y - RMAX) * 64.f));
        int cy1 = min(63, (int)ceilf((a.w + RMAX) * 64.f) - 1);
        unsigned bit = 1u << (g & 31);
        const int word = (g >> 5);
        for (int cy = cy0 + strip; cy <= cy1; cy += 16)
            for (int cx = cx0; cx <= cx1; cx++)
                atomicOr(&msk[2 * (cy * 64 + cx) + word], bit);
    }
    __syncthreads();

#pragma unroll
    for (int j = 0; j < 4; j++) {
        const int p = chunk * CPR + j * 1024 + tid;
        float4 pr = *reinterpret_cast<const float4*>(priorbox + (size_t)p * 4);
        float hx = 0.5f * pr.z, hy = 0.5f * pr.w;
        float px1 = pr.x - hx, py1 = pr.y - hy;
        float px2 = pr.x + hx, py2 = pr.y + hy;
        float par = (px2 - px1) * (py2 - py1);
        int cx = min(63, max(0, (int)(pr.x * 64.f)));
        int cy = min(63, max(0, (int)(pr.y * 64.f)));
        uint2 mm = *reinterpret_cast<uint2*>(&msk[2 * (cy * 64 + cx)]);
        unsigned long long m = ((unsigned long long)mm.y << 32) | mm.x;
        const unsigned long long notp = (unsigned long long)(~(unsigned)p);
        float bv = -1.f; int bg = 0;
        while (m) {
            // two set bits per iteration: two independent LDS reads in flight
            const int g0 = __ffsll(m) - 1; m &= m - 1;
            const bool has1 = (m != 0ull);
            const int g1 = has1 ? (__ffsll(m) - 1) : g0;
            if (has1) m &= m - 1;
            float4 a0 = gxy[g0];
            float4 a1 = gxy[g1];
            float w0 = fmaxf(fminf(a0.z, px2) - fmaxf(a0.x, px1), 0.f);
            float h0 = fmaxf(fminf(a0.w, py2) - fmaxf(a0.y, py1), 0.f);
            float w1 = fmaxf(fminf(a1.z, px2) - fmaxf(a1.x, px1), 0.f);
            float h1 = fmaxf(fminf(a1.w, py2) - fmaxf(a1.y, py1), 0.f);
            float ar0 = (a0.z - a0.x) * (a0.w - a0.y);
            float ar1 = (a1.z - a1.x) * (a1.w - a1.y);
            float i0 = w0 * h0, i1 = w1 * h1;
            float v0 = i0 * __builtin_amdgcn_rcpf(ar0 + par - i0);
            float v1 = i1 * __builtin_amdgcn_rcpf(ar1 + par - i1);
            if (v0 > bv) { bv = v0; bg = g0; }          // ascending g: first-max kept
            if (has1 && v1 > bv) { bv = v1; bg = g1; }
            if (v0 > 0.f)
                atomicMax(&sbest[g0],
                          (((unsigned long long)__float_as_uint(v0)) << 32) | notp);
            if (has1 && v1 > 0.f)
                atomicMax(&sbest[g1],
                          (((unsigned long long)__float_as_uint(v1)) << 32) | notp);
        }
        pu8[(size_t)b * PP + p] = (unsigned char)(bg | ((bv >= THRESH) ? 0x80 : 0));
    }

    __syncthreads();
    if (tid < GG) bestp[(b * NCH + chunk) * GG + tid] = sbest[tid];   // plain store
}

// ---------------- kernel 2: reduce bestp + loss + keys + global hist ----------------
// grid (NCH, BB) x 1024; 4 priors/thread strided by 1024.
__global__ __launch_bounds__(1024, 8) void k_loss(
    const float* __restrict__ loc_preds, const float* __restrict__ cls_preds,
    const float* __restrict__ priorbox, const float* __restrict__ targets,
    const unsigned long long* __restrict__ bestp, const unsigned char* __restrict__ pu8,
    unsigned* __restrict__ keys, unsigned* __restrict__ h1tot,
    int* __restrict__ nposp, float* __restrict__ pcp, float* __restrict__ locp,
    unsigned* __restrict__ cidx, float* __restrict__ negs,
    unsigned* __restrict__ arr, unsigned* __restrict__ done)
{
    __shared__ unsigned long long tmp64[2048];
    __shared__ unsigned hcnt[4096];
    __shared__ unsigned char ovr[CPR];                 // forced-pos override table
    __shared__ float4 gxy[GG];
    __shared__ float glab[GG];
    __shared__ float sred[32];
    __shared__ int sredi[16];
    const int b = blockIdx.y, chunk = blockIdx.x, tid = threadIdx.x;
    const int lane = tid & 63, wid = tid >> 6;

    if (tid == 0 && chunk == 0) {                      // zero sync state for k_tail
        cidx[b] = 0u; negs[b] = 0.f; arr[b] = 0u;
        if (b == 0) *done = 0u;
    }

    tmp64[tid]        = bestp[(b * NCH + (tid >> 6)) * GG + (tid & 63)];
    tmp64[tid + 1024] = bestp[(b * NCH + 16 + (tid >> 6)) * GG + (tid & 63)];
    for (int i = tid; i < 4096; i += 1024) { hcnt[i] = 0u; ovr[i] = 0xFF; }
    if (tid < GG) {
        const float* t = targets + (size_t)(b * GG + tid) * 5;
        gxy[tid] = make_float4(t[1], t[0], t[3], t[2]);
        glab[tid] = t[4];
    }
    __syncthreads();
    for (int s = 16; s > 0; s >>= 1) {                 // reduce chunk dim 32 -> 1
        if (tid < s * 64) {
            const int c = tid >> 6, g = tid & 63;
            unsigned long long a = tmp64[c * 64 + g], d = tmp64[(c + s) * 64 + g];
            tmp64[c * 64 + g] = d > a ? d : a;
        }
        __syncthreads();
    }
    if (tid == 0) {
        for (int g = 0; g < GG; g++) {                 // ascending g: later-g wins
            unsigned long long m = tmp64[g];
            if (m) {
                unsigned p = ~((unsigned)(m & 0xFFFFFFFFull));
                if ((int)(p >> 12) == chunk) ovr[p & (CPR - 1)] = (unsigned char)g;
            }
        }
    }
    __syncthreads();

    float locpart = 0.f, clspart = 0.f; int cnt = 0;
#pragma unroll
    for (int j = 0; j < 4; j++) {
        const int plocal = j * 1024 + tid;
        const size_t ip = (size_t)b * PP + chunk * CPR + plocal;
        const unsigned m8 = pu8[ip];
        int g = m8 & 63;
        bool pos = (m8 >> 7) != 0;
        const unsigned o = ovr[plocal];                // 1 LDS byte vs 64-entry scan
        if (o != 0xFFu) { pos = true; g = (int)o; }
        const float2 cl = *reinterpret_cast<const float2*>(cls_preds + ip * 2);
        const float mx = fmaxf(cl.x, cl.y);
        const float lse = mx + log1pf(expf(fminf(cl.x, cl.y) - mx));
        unsigned key = 0u;
        if (pos && glab[g] > 0.f) {
            float gathered = (((int)glab[g]) == 0) ? cl.x : cl.y;
            clspart += lse - gathered;
            cnt++;
            const int p = chunk * CPR + plocal;
            float4 pr = *reinterpret_cast<const float4*>(priorbox + (size_t)p * 4);
            float4 gt = gxy[g];
            float gcx = ((gt.x + gt.z) * 0.5f - pr.x) / (0.1f * pr.z);
            float gcy = ((gt.y + gt.w) * 0.5f - pr.y) / (0.1f * pr.w);
            float gw = logf((gt.z - gt.x) / pr.z) / 0.2f;
            float gh = logf((gt.w - gt.y) / pr.w) / 0.2f;
            float4 lp = *reinterpret_cast<const float4*>(loc_preds + ip * 4);
            float d0 = lp.x - gcx, d1 = lp.y - gcy, d2 = lp.z - gw, d3 = lp.w - gh;
            float a0 = fabsf(d0), a1 = fabsf(d1), a2 = fabsf(d2), a3 = fabsf(d3);
            locpart += ((a0 < 1.f) ? 0.5f * d0 * d0 : a0 - 0.5f)
                     + ((a1 < 1.f) ? 0.5f * d1 * d1 : a1 - 0.5f)
                     + ((a2 < 1.f) ? 0.5f * d2 * d2 : a2 - 0.5f)
                     + ((a3 < 1.f) ? 0.5f * d3 * d3 : a3 - 0.5f);
        } else {
            float lc = lse - cl.x;                     // > 0 strictly for negs
            key = __float_as_uint(lc);
            atomicAdd(&hcnt[key >> 20], 1u);           // counts only
        }
        keys[ip] = key;
    }

    for (int o = 32; o; o >>= 1) {
        locpart += __shfl_xor(locpart, o);
        clspart += __shfl_xor(clspart, o);
        cnt     += __shfl_xor(cnt, o);
    }
    if (lane == 0) { sred[wid] = locpart; sred[16 + wid] = clspart; sredi[wid] = cnt; }
    __syncthreads();
    if (tid == 0) {
        float l = 0.f, c = 0.f; int n = 0;
        for (int i = 0; i < 16; i++) { l += sred[i]; c += sred[16 + i]; n += sredi[i]; }
        nposp[b * NCH + chunk] = n;                    // unconditional: no init needed
        pcp[b * NCH + chunk] = c;
        locp[b * NCH + chunk] = l;
    }
    __syncthreads();
    for (int i = tid; i < 4096; i += 1024) {           // ~400 nonzero bins/block
        unsigned cc = hcnt[i];
        if (cc) atomicAdd(&h1tot[b * 4096 + i], cc);
    }
}

// ---------------- parallel descending k-th finder (1024-thread block) ----------------
template <int NBINS>
__device__ void find_kth_par(const unsigned* __restrict__ h, int k, int* sel, int* krem)
{
    constexpr int PER = NBINS / 1024;
    __shared__ unsigned wsum_[16];
    __shared__ int res_[2];
    const int tid = threadIdx.x, lane = tid & 63, wid = tid >> 6;
    __syncthreads();
    unsigned own[PER];
    unsigned s = 0;
#pragma unroll
    for (int i = 0; i < PER; i++) { own[i] = h[NBINS - 1 - (tid * PER + i)]; s += own[i]; }
    unsigned incl = s;
    for (int d = 1; d < 64; d <<= 1) {
        unsigned t = __shfl_up(incl, d);
        if (lane >= d) incl += t;
    }
    if (lane == 63) wsum_[wid] = incl;
    if (tid == 0) { res_[0] = -1; res_[1] = 0; }
    __syncthreads();
    unsigned woff = 0;
    for (int w = 0; w < 16; w++) woff += (w < wid) ? wsum_[w] : 0u;
    const unsigned texcl = woff + incl - s;
    if (k > 0 && texcl < (unsigned)k && texcl + s >= (unsigned)k) {
        unsigned run = texcl;
#pragma unroll
        for (int i = 0; i < PER; i++) {
            run += own[i];
            if (run >= (unsigned)k) {
                res_[0] = NBINS - 1 - (tid * PER + i);
                res_[1] = k - (int)(run - own[i]);
                break;
            }
        }
    }
    __syncthreads();
    *sel = res_[0]; *krem = res_[1];
}

__device__ float block_sum_f(float v)
{
    __shared__ float rs[16];
    const int tid = threadIdx.x;
    __syncthreads();
    for (int o = 32; o; o >>= 1) v += __shfl_xor(v, o);
    if ((tid & 63) == 0) rs[tid >> 6] = v;
    __syncthreads();
    float s = 0.f;
    for (int i = 0; i < 16; i++) s += rs[i];
    return s;
}

// ---------------- kernel 3: compact + negsum; last block/image does select+final ----
// grid (NCT, BB) x 1024, 8 keys/thread.
__global__ __launch_bounds__(1024) void k_tail(
    const unsigned* __restrict__ keys, const unsigned* __restrict__ h1tot,
    const int* __restrict__ nposp, const float* __restrict__ pcp,
    const float* __restrict__ locp, unsigned* __restrict__ cand,
    unsigned* __restrict__ cidx, float* __restrict__ negs,
    unsigned* __restrict__ arr, unsigned* __restrict__ done,
    int* __restrict__ resn, int* __restrict__ resk,
    float* __restrict__ resc, float* __restrict__ resl, float* __restrict__ out)
{
    __shared__ unsigned wcnt[16], wbase[16];
    __shared__ unsigned bbase;
    __shared__ int snp, lastflag;
    __shared__ unsigned ch[1024];
    __shared__ float cs[1024];
    const int b = blockIdx.y, chunk = blockIdx.x, tid = threadIdx.x;
    const int lane = tid & 63, wid = tid >> 6;

    if (tid == 0) {
        int np = 0;
        for (int c = 0; c < NCH; c++) np += nposp[b * NCH + c];
        snp = np;
    }
    unsigned kv[8];
#pragma unroll
    for (int j = 0; j < 8; j++)
        kv[j] = keys[(size_t)b * PP + chunk * CPT + j * 1024 + tid];
    __syncthreads();
    const int np = snp;
    const int k = min(3 * np, PP - 1);
    int sel1, kk1;
    find_kth_par<4096>(h1tot + b * 4096, k, &sel1, &kk1);
    const unsigned s1 = (unsigned)sel1;                // -1 matches nothing

    // negsum over buckets strictly above sel1, straight from registers
    float nv = 0.f;
    if (sel1 >= 0) {
#pragma unroll
        for (int j = 0; j < 8; j++)
            if ((kv[j] >> 20) > s1) nv += __uint_as_float(kv[j]);
    }
    float nsum = block_sum_f(nv);
    if (tid == 0 && nsum != 0.f) atomicAdd(&negs[b], nsum);   // 16 adds/address

    // compact bucket-sel1 keys: 1 returning atomic per block
    unsigned long long mv[8];
    unsigned wn = 0;
#pragma unroll
    for (int j = 0; j < 8; j++) {
        mv[j] = __ballot((kv[j] >> 20) == s1);
        wn += (unsigned)__popcll(mv[j]);
    }
    if (lane == 0) wcnt[wid] = wn;
    __syncthreads();
    if (tid == 0) {
        unsigned run = 0;
        for (int w = 0; w < 16; w++) { wbase[w] = run; run += wcnt[w]; }
        bbase = run ? atomicAdd(&cidx[b], run) : 0u;
    }
    __syncthreads();
    {
        unsigned run = bbase + wbase[wid];
        const unsigned long long lanemask = (1ull << lane) - 1ull;
#pragma unroll
        for (int j = 0; j < 8; j++) {
            if ((kv[j] >> 20) == s1)
                cand[(size_t)b * PP + run + (unsigned)__popcll(mv[j] & lanemask)] = kv[j];
            run += (unsigned)__popcll(mv[j]);
        }
    }

    // arrival: the 16th block of this image runs the select phase.
    // Fences are tid0-ONLY (L1 is per-CU, shared by the block; R10's
    // all-thread __threadfence here was 256 waves x device fence = ~40 us).
    __syncthreads();
    if (tid == 0) {
        __threadfence();                               // release cand/negs writes
        unsigned old = atomicAdd(&arr[b], 1u);
        lastflag = (old == NCT - 1) ? 1 : 0;
    }
    __syncthreads();
    if (!lastflag) return;
    if (tid == 0) __threadfence();                     // acquire (tid0-only)
    __syncthreads();

    const unsigned ncand = cidx[b];
    ch[tid] = 0u; cs[tid] = 0.f;
    __syncthreads();
    for (unsigned i = tid; i < ncand; i += 1024) {
        unsigned v = cand[(size_t)b * PP + i];
        unsigned bin = (v >> 10) & 1023u;
        atomicAdd(&ch[bin], 1u);
        atomicAdd(&cs[bin], __uint_as_float(v));
    }
    __syncthreads();
    int sel2, kk2;
    find_kth_par<1024>(ch, (sel1 < 0) ? 0 : kk1, &sel2, &kk2);
    float sumhi2 = block_sum_f((sel2 >= 0 && tid > sel2) ? cs[tid] : 0.f);

    __syncthreads();
    ch[tid] = 0u; cs[tid] = 0.f;
    __syncthreads();
    if (sel2 >= 0) {
        for (unsigned i = tid; i < ncand; i += 1024) {
            unsigned v = cand[(size_t)b * PP + i];
            if (((v >> 10) & 1023u) == (unsigned)sel2) {
                atomicAdd(&ch[v & 1023u], 1u);
                atomicAdd(&cs[v & 1023u], __uint_as_float(v));
            }
        }
    }
    __syncthreads();
    int sel3, needeq;
    find_kth_par<1024>(ch, (sel2 < 0) ? 0 : kk2, &sel3, &needeq);
    float sumhi3 = block_sum_f((sel3 >= 0 && tid > sel3) ? cs[tid] : 0.f);

    if (tid == 0) {
        float pcsum = 0.f, locsum = 0.f;
        for (int c = 0; c < NCH; c++) {
            pcsum += pcp[b * NCH + c];
            locsum += locp[b * NCH + c];
        }
        float add = 0.f;
        if (sel3 >= 0 && needeq > 0) {
            unsigned Kstar = ((unsigned)sel1 << 20) | ((unsigned)sel2 << 10) | (unsigned)sel3;
            add = needeq * __uint_as_float(Kstar);
        }
        resn[b] = np;
        resk[b] = k;
        resc[b] = pcsum + negs[b] + sumhi2 + sumhi3 + add;
        resl[b] = locsum;
        __threadfence();
        unsigned old = atomicAdd(done, 1u);
        lastflag = (old == BB - 1) ? 1 : 0;
    }
    __syncthreads();
    if (!lastflag || tid != 0) return;

    __threadfence();
    volatile int* vrn = (volatile int*)resn;
    volatile int* vrk = (volatile int*)resk;
    volatile float* vrc = (volatile float*)resc;
    volatile float* vrl = (volatile float*)resl;
    int npt = 0; long long maskc = 0; float clsnum = 0.f, locnum = 0.f;
    for (int b2 = 0; b2 < BB; b2++) {
        npt += vrn[b2];
        maskc += (long long)vrn[b2] + vrk[b2];
        clsnum += vrc[b2];
        locnum += vrl[b2];
    }
    float denom_loc = (float)((4 * npt > 1) ? 4 * npt : 1);
    float denom_cls = (float)((maskc > 1) ? maskc : 1);
    float loss_loc = locnum / denom_loc;
    float loss_cls = clsnum / denom_cls;
    out[0] = (loss_cls + loss_loc) / (float)npt;
    out[1] = loss_loc;
    out[2] = loss_cls;
}

extern "C" void kernel_launch(void* const* d_in, const int* in_sizes, int n_in,
                              void* d_out, int out_size, void* d_ws, size_t ws_size,
                              hipStream_t stream)
{
    const float* loc_preds = (const float*)d_in[0];
    const float* cls_preds = (const float*)d_in[1];
    const float* priorbox  = (const float*)d_in[2];
    const float* targets   = (const float*)d_in[3];
    float* out = (float*)d_out;

    char* ws = (char*)d_ws;
    unsigned long long* bestp = (unsigned long long*)(ws + OFF_BESTP);
    unsigned* h1tot = (unsigned*)(ws + OFF_H1TOT);
    int*      nposp = (int*)(ws + OFF_NPOSP);
    float*    pcp   = (float*)(ws + OFF_PCP);
    float*    locp  = (float*)(ws + OFF_LOCP);
    unsigned* cidx  = (unsigned*)(ws + OFF_CIDX);
    float*    negs  = (float*)(ws + OFF_NEGS);
    unsigned* arr   = (unsigned*)(ws + OFF_ARR);
    unsigned* done  = (unsigned*)(ws + OFF_DONE);
    int*      resn  = (int*)(ws + OFF_RESN);
    int*      resk  = (int*)(ws + OFF_RESK);
    float*    resc  = (float*)(ws + OFF_RESC);
    float*    resl  = (float*)(ws + OFF_RESL);
    unsigned char* pu8 = (unsigned char*)(ws + OFF_PU8);
    unsigned* keys  = (unsigned*)(ws + OFF_KEYS);
    unsigned* cand  = (unsigned*)(ws + OFF_CAND);

    k_match<<<dim3(NCH, BB), 1024, 0, stream>>>(priorbox, targets, bestp, pu8, h1tot);
    k_loss<<<dim3(NCH, BB), 1024, 0, stream>>>(loc_preds, cls_preds, priorbox, targets,
                                               bestp, pu8, keys, h1tot,
                                               nposp, pcp, locp, cidx, negs, arr, done);
    k_tail<<<dim3(NCT, BB), 1024, 0, stream>>>(keys, h1tot, nposp, pcp, locp, cand,
                                               cidx, negs, arr, done,
                                               resn, resk, resc, resl, out);
}